// Round 1
// baseline (404.551 us; speedup 1.0000x reference)
//
#include <hip/hip_runtime.h>
#include <stdint.h>

// Problem constants: B=8, S=2048, IN=4096, OUT=64, L=16
#define NB   8
#define NS   2048
#define NIN  4096
#define NOUT 64
#define NL   16

constexpr int MT = 16;         // m rows per block
constexpr int KT = 128;        // k floats per tile
constexpr int NT = NIN / KT;   // 32 tiles

typedef __attribute__((ext_vector_type(8))) short  s16x8;   // MFMA A/B frag (8 bf16)
typedef __attribute__((ext_vector_type(4))) float  f32x4;   // MFMA acc
typedef __attribute__((ext_vector_type(4))) float  fv4;
typedef __attribute__((ext_vector_type(4))) __bf16 bf16x4;

// 8 fp32 -> 8 bf16 RNE via v_cvt_pk_bf16_f32 (1 inst / 2 elems).
__device__ __forceinline__ s16x8 cvt8(float4 a, float4 b) {
    fv4 va = {a.x, a.y, a.z, a.w};
    fv4 vb = {b.x, b.y, b.z, b.w};
    union { struct { bf16x4 lo, hi; } h; s16x8 s; } u;
    u.h.lo = __builtin_convertvector(va, bf16x4);
    u.h.hi = __builtin_convertvector(vb, bf16x4);
    return u.s;
}

// Multi-LoRA linear, m97-style: x staged fp32->bf16 into XOR-swizzled LDS,
// double-buffered, one __syncthreads per K=128 tile; latency hidden by
// 4 blocks/CU overlapping each other's barrier drains (m114 mechanism).
//
// THIS ROUND: no workspace, no pre-convert kernel. Weights are read as fp32
// (L2-resident per XCD: 1 MiB/adapter, one adapter per XCD via bx&7) and
// RNE-converted to bf16 in-register (identical math to the old ws path).
// Purpose: the timed region contained two 1-GiB d_ws poison fills (~320 us);
// removing all ws use tests whether that poison is conditional on ws usage.
//
// Grid: 1024 = 8 batches (XCD-affine via bx&7) x 128 m-tiles of 16 rows.
// Block: 256 threads = 4 waves; wave wv computes out[16 m][wv*16 .. +16).
//   A-frag: x[m = lane&15][k = (lane>>4)*8 + j]  (bf16, from LDS)
//   B-frag: w[n = lane&15 + wv*16][same k]       (bf16 from fp32, L2-hot)
//   D:      col = lane&15 (n), row = (lane>>4)*4 + reg (m)   [verified r1]
__global__ __launch_bounds__(256, 4) void mll_kernel(const float* __restrict__ x,
                                                     const int* __restrict__ ids,
                                                     const float* __restrict__ w,
                                                     float* __restrict__ out) {
    // [2 buf][16 rows][128 bf16], 16B chunks XOR-swizzled by row -> 2-way banks (free)
    __shared__ __align__(16) unsigned short xs[2 * MT * KT];  // 8 KB

    const int bx   = blockIdx.x;
    const int b    = bx & 7;       // batch; round-robin dispatch -> XCD-affine
    const int mt   = bx >> 3;      // 0..127
    const int aid  = ids[b];
    const int t    = threadIdx.x;
    const int lane = t & 63;
    const int wv   = t >> 6;
    const int l15  = lane & 15;
    const int lk   = lane >> 4;    // 0..3

    // ---- staging coords: thread t loads row t>>4, 8-float chunk q = t&15
    const int srow = t >> 4;       // 0..15
    const int sq   = t & 15;       // 0..15
    const float* gsrc = x + ((size_t)(b * NS + mt * MT + srow)) * NIN + sq * 8;
    const int woff = srow * KT + ((sq ^ srow) * 8);   // swizzled LDS elem offset

    // ---- A-frag LDS read offsets (per K=32 step s: chunk q = s*4+lk)
    int roff[4];
#pragma unroll
    for (int s = 0; s < 4; ++s) roff[s] = l15 * KT + (((s * 4 + lk) ^ l15) * 8);

    // ---- B pointer (fp32, converted in-register)
    const float* wb32 = w + ((size_t)(aid * NOUT + wv * 16 + l15)) * NIN + lk * 8;

    f32x4 acc = {0.f, 0.f, 0.f, 0.f};

#define LOAD_B(dst, tt)                                                        \
    _Pragma("unroll")                                                          \
    for (int s = 0; s < 4; ++s) {                                              \
        const float4* _wp = (const float4*)(wb32 + (size_t)(tt) * KT + s * 32); \
        dst[s] = cvt8(_wp[0], _wp[1]);                                         \
    }

    // ---- prologue: tile 0 -> LDS buf0; tile 1 -> regs; B tile 0 -> regs
    {
        const float4* g0 = (const float4*)gsrc;
        *(s16x8*)(xs + woff) = cvt8(g0[0], g0[1]);
    }
    const float4* g1 = (const float4*)(gsrc + KT);
    float4 r0 = g1[0], r1 = g1[1];
    s16x8 bcur[4], bnext[4];
    LOAD_B(bcur, 0);
    __syncthreads();

    for (int tile = 0; tile < NT; ++tile) {
        const int p = tile & 1;

        // prefetch x tile+2 (clamped; tail reload harmless) — used next iter's write
        const int pt = (tile + 2 < NT) ? (tile + 2) : (NT - 1);
        const float4* gn = (const float4*)(gsrc + (size_t)pt * KT);
        float4 n0 = gn[0], n1 = gn[1];

        // prefetch B tile+1 (clamped)
        const int bt = (tile + 1 < NT) ? (tile + 1) : (NT - 1);
        LOAD_B(bnext, bt);

        // compute tile from LDS buf p (4 K=32 MFMA steps)
        const unsigned short* buf = xs + p * (MT * KT);
#pragma unroll
        for (int s = 0; s < 4; ++s) {
            s16x8 af = *(const s16x8*)(buf + roff[s]);
            acc = __builtin_amdgcn_mfma_f32_16x16x32_bf16(af, bcur[s], acc, 0, 0, 0);
        }

        // stage tile+1 (in r0/r1 since last iter) into the other buffer
        if (tile + 1 < NT) {
            *(s16x8*)(xs + (1 - p) * (MT * KT) + woff) = cvt8(r0, r1);
        }
        r0 = n0; r1 = n1;
#pragma unroll
        for (int s = 0; s < 4; ++s) bcur[s] = bnext[s];
        __syncthreads();
    }
#undef LOAD_B

    // ---- store: D col = lane&15 (n), row = (lane>>4)*4 + reg (m)
    float* ob = out + ((size_t)(b * NS + mt * MT)) * NOUT + wv * 16 + l15;
#pragma unroll
    for (int r = 0; r < 4; ++r) {
        ob[(size_t)(lk * 4 + r) * NOUT] = acc[r];
    }
}

extern "C" void kernel_launch(void* const* d_in, const int* in_sizes, int n_in,
                              void* d_out, int out_size, void* d_ws, size_t ws_size,
                              hipStream_t stream) {
    const float* x   = (const float*)d_in[0];
    const int*   ids = (const int*)d_in[1];
    const float* w   = (const float*)d_in[2];
    float*       out = (float*)d_out;

    (void)d_ws; (void)ws_size;  // deliberately unused: testing ws-poison hypothesis

    const int grid = NB * (NS / MT);  // 1024
    mll_kernel<<<grid, 256, 0, stream>>>(x, ids, w, out);
}

// Round 2
// 375.401 us; speedup vs baseline: 1.0776x; 1.0776x over previous
//
#include <hip/hip_runtime.h>
#include <stdint.h>

// Problem constants: B=8, S=2048, IN=4096, OUT=64, L=16
#define NB   8
#define NS   2048
#define NIN  4096
#define NOUT 64
#define NL   16

constexpr int MT = 16;         // m rows per block
constexpr int KT = 128;        // k floats per tile
constexpr int NT = NIN / KT;   // 32 tiles

typedef __attribute__((ext_vector_type(8))) short  s16x8;   // MFMA A/B frag (8 bf16)
typedef __attribute__((ext_vector_type(4))) float  f32x4;   // MFMA acc
typedef __attribute__((ext_vector_type(4))) float  fv4;
typedef __attribute__((ext_vector_type(4))) __bf16 bf16x4;

// 8 fp32 -> 8 bf16 RNE via v_cvt_pk_bf16_f32 (1 inst / 2 elems).
__device__ __forceinline__ s16x8 cvt8(float4 a, float4 b) {
    fv4 va = {a.x, a.y, a.z, a.w};
    fv4 vb = {b.x, b.y, b.z, b.w};
    union { struct { bf16x4 lo, hi; } h; s16x8 s; } u;
    u.h.lo = __builtin_convertvector(va, bf16x4);
    u.h.hi = __builtin_convertvector(vb, bf16x4);
    return u.s;
}

// Pre-kernel: gather + convert ONLY the used adapters, per batch slot.
// ws layout: [B=8][OUT=64][IN=4096] bf16 (4 MiB). Reads 8 MiB fp32 instead of
// the old all-16-adapters 16 MiB (convert traffic 24 -> 12 MiB, ~2 us saved).
// Duplicate adapter ids write distinct slots -> no race.
// Grid: 8 batches x 128 chunks; 8 elems/thread.
__global__ __launch_bounds__(256) void convert_w_kernel(const float* __restrict__ w,
                                                        const int* __restrict__ ids,
                                                        unsigned short* __restrict__ o) {
    const int b     = blockIdx.x >> 7;                  // 0..7
    const int chunk = blockIdx.x & 127;                 // 0..127
    const int aid   = ids[b];
    const size_t i  = ((size_t)chunk * 256 + threadIdx.x) * 8;  // elem in [0, 262144)
    const float4* src = (const float4*)(w + (size_t)aid * NOUT * NIN + i);
    *(s16x8*)(o + (size_t)b * NOUT * NIN + i) = cvt8(src[0], src[1]);
}

// Multi-LoRA linear, m97-style: x staged fp32->bf16 into XOR-swizzled LDS,
// double-buffered, one __syncthreads per K=128 tile; latency hidden by
// 4 blocks/CU overlapping each other's barrier drains (m114 mechanism).
//
// NOTE (r0/r1 finding): the harness re-poisons the 1 GiB workspace with two
// ~161 us fills inside the timed region UNCONDITIONALLY (verified r1: fills
// persist with d_ws untouched). Reported dur_us = ~322 us fixed + our work.
// The bf16-ws path (54 us of work) beats in-loop fp32->bf16 B conversion
// (82 us, r1), so the workspace structure stays.
//
// Grid: 1024 = 8 batches (XCD-affine via bx&7) x 128 m-tiles of 16 rows.
// Block: 256 threads = 4 waves; wave wv computes out[16 m][wv*16 .. +16).
//   A-frag: x[m = lane&15][k = (lane>>4)*8 + j]  (bf16, from LDS)
//   B-frag: ws[b][n = lane&15 + wv*16][same k]   (bf16, from global, L2-hot)
//   D:      col = lane&15 (n), row = (lane>>4)*4 + reg (m)
__global__ __launch_bounds__(256, 4) void mll_kernel(const float* __restrict__ x,
                                                     const unsigned short* __restrict__ wb,
                                                     float* __restrict__ out) {
    // [2 buf][16 rows][128 bf16], 16B chunks XOR-swizzled by row -> 2-way banks (free)
    __shared__ __align__(16) unsigned short xs[2 * MT * KT];  // 8 KB

    const int bx   = blockIdx.x;
    const int b    = bx & 7;       // batch; round-robin dispatch -> XCD-affine
    const int mt   = bx >> 3;      // 0..127
    const int t    = threadIdx.x;
    const int lane = t & 63;
    const int wv   = t >> 6;
    const int l15  = lane & 15;
    const int lk   = lane >> 4;    // 0..3

    // ---- staging coords: thread t loads row t>>4, 8-float chunk q = t&15
    const int srow = t >> 4;       // 0..15
    const int sq   = t & 15;       // 0..15
    const float* gsrc = x + ((size_t)(b * NS + mt * MT + srow)) * NIN + sq * 8;
    const int woff = srow * KT + ((sq ^ srow) * 8);   // swizzled LDS elem offset

    // ---- A-frag LDS read offsets (per K=32 step s: chunk q = s*4+lk)
    int roff[4];
#pragma unroll
    for (int s = 0; s < 4; ++s) roff[s] = l15 * KT + (((s * 4 + lk) ^ l15) * 8);

    // ---- B pointer: per-batch slot in ws (bf16)
    const unsigned short* wb16 = wb + ((size_t)(b * NOUT + wv * 16 + l15)) * NIN + lk * 8;

    f32x4 acc = {0.f, 0.f, 0.f, 0.f};

#define LOAD_B(dst, tt)                                                        \
    _Pragma("unroll")                                                          \
    for (int s = 0; s < 4; ++s)                                                \
        dst[s] = *(const s16x8*)(wb16 + (size_t)(tt) * KT + s * 32);

    // ---- prologue: tile 0 -> LDS buf0; tile 1 -> regs; B tile 0 -> regs
    {
        const float4* g0 = (const float4*)gsrc;
        *(s16x8*)(xs + woff) = cvt8(g0[0], g0[1]);
    }
    const float4* g1 = (const float4*)(gsrc + KT);
    float4 r0 = g1[0], r1 = g1[1];
    s16x8 bcur[4], bnext[4];
    LOAD_B(bcur, 0);
    __syncthreads();

    for (int tile = 0; tile < NT; ++tile) {
        const int p = tile & 1;

        // prefetch x tile+2 (clamped; tail reload harmless) — used next iter's write
        const int pt = (tile + 2 < NT) ? (tile + 2) : (NT - 1);
        const float4* gn = (const float4*)(gsrc + (size_t)pt * KT);
        float4 n0 = gn[0], n1 = gn[1];

        // prefetch B tile+1 (clamped)
        const int bt = (tile + 1 < NT) ? (tile + 1) : (NT - 1);
        LOAD_B(bnext, bt);

        // compute tile from LDS buf p (4 K=32 MFMA steps)
        const unsigned short* buf = xs + p * (MT * KT);
#pragma unroll
        for (int s = 0; s < 4; ++s) {
            s16x8 af = *(const s16x8*)(buf + roff[s]);
            acc = __builtin_amdgcn_mfma_f32_16x16x32_bf16(af, bcur[s], acc, 0, 0, 0);
        }

        // stage tile+1 (in r0/r1 since last iter) into the other buffer
        if (tile + 1 < NT) {
            *(s16x8*)(xs + (1 - p) * (MT * KT) + woff) = cvt8(r0, r1);
        }
        r0 = n0; r1 = n1;
#pragma unroll
        for (int s = 0; s < 4; ++s) bcur[s] = bnext[s];
        __syncthreads();
    }
#undef LOAD_B

    // ---- store: D col = lane&15 (n), row = (lane>>4)*4 + reg (m)
    float* ob = out + ((size_t)(b * NS + mt * MT)) * NOUT + wv * 16 + l15;
#pragma unroll
    for (int r = 0; r < 4; ++r) {
        ob[(size_t)(lk * 4 + r) * NOUT] = acc[r];
    }
}

// Fallback (no workspace): fp32 weights converted in-register (r1 variant).
__global__ __launch_bounds__(256, 4) void mll_kernel_f32(const float* __restrict__ x,
                                                         const int* __restrict__ ids,
                                                         const float* __restrict__ w,
                                                         float* __restrict__ out) {
    __shared__ __align__(16) unsigned short xs[2 * MT * KT];

    const int bx   = blockIdx.x;
    const int b    = bx & 7;
    const int mt   = bx >> 3;
    const int aid  = ids[b];
    const int t    = threadIdx.x;
    const int lane = t & 63;
    const int wv   = t >> 6;
    const int l15  = lane & 15;
    const int lk   = lane >> 4;

    const int srow = t >> 4;
    const int sq   = t & 15;
    const float* gsrc = x + ((size_t)(b * NS + mt * MT + srow)) * NIN + sq * 8;
    const int woff = srow * KT + ((sq ^ srow) * 8);

    int roff[4];
#pragma unroll
    for (int s = 0; s < 4; ++s) roff[s] = l15 * KT + (((s * 4 + lk) ^ l15) * 8);

    const float* wb32 = w + ((size_t)(aid * NOUT + wv * 16 + l15)) * NIN + lk * 8;

    f32x4 acc = {0.f, 0.f, 0.f, 0.f};

#define LOAD_B(dst, tt)                                                        \
    _Pragma("unroll")                                                          \
    for (int s = 0; s < 4; ++s) {                                              \
        const float4* _wp = (const float4*)(wb32 + (size_t)(tt) * KT + s * 32); \
        dst[s] = cvt8(_wp[0], _wp[1]);                                         \
    }

    {
        const float4* g0 = (const float4*)gsrc;
        *(s16x8*)(xs + woff) = cvt8(g0[0], g0[1]);
    }
    const float4* g1 = (const float4*)(gsrc + KT);
    float4 r0 = g1[0], r1 = g1[1];
    s16x8 bcur[4], bnext[4];
    LOAD_B(bcur, 0);
    __syncthreads();

    for (int tile = 0; tile < NT; ++tile) {
        const int p = tile & 1;
        const int pt = (tile + 2 < NT) ? (tile + 2) : (NT - 1);
        const float4* gn = (const float4*)(gsrc + (size_t)pt * KT);
        float4 n0 = gn[0], n1 = gn[1];
        const int bt = (tile + 1 < NT) ? (tile + 1) : (NT - 1);
        LOAD_B(bnext, bt);

        const unsigned short* buf = xs + p * (MT * KT);
#pragma unroll
        for (int s = 0; s < 4; ++s) {
            s16x8 af = *(const s16x8*)(buf + roff[s]);
            acc = __builtin_amdgcn_mfma_f32_16x16x32_bf16(af, bcur[s], acc, 0, 0, 0);
        }
        if (tile + 1 < NT) {
            *(s16x8*)(xs + (1 - p) * (MT * KT) + woff) = cvt8(r0, r1);
        }
        r0 = n0; r1 = n1;
#pragma unroll
        for (int s = 0; s < 4; ++s) bcur[s] = bnext[s];
        __syncthreads();
    }
#undef LOAD_B

    float* ob = out + ((size_t)(b * NS + mt * MT)) * NOUT + wv * 16 + l15;
#pragma unroll
    for (int r = 0; r < 4; ++r) {
        ob[(size_t)(lk * 4 + r) * NOUT] = acc[r];
    }
}

extern "C" void kernel_launch(void* const* d_in, const int* in_sizes, int n_in,
                              void* d_out, int out_size, void* d_ws, size_t ws_size,
                              hipStream_t stream) {
    const float* x   = (const float*)d_in[0];
    const int*   ids = (const int*)d_in[1];
    const float* w   = (const float*)d_in[2];
    float*       out = (float*)d_out;

    const size_t wbytes = (size_t)NB * NOUT * NIN * sizeof(unsigned short);  // 4 MiB
    const int grid = NB * (NS / MT);  // 1024

    if (ws_size >= wbytes) {
        unsigned short* wbf = (unsigned short*)d_ws;
        convert_w_kernel<<<NB * 128, 256, 0, stream>>>(w, ids, wbf);
        mll_kernel<<<grid, 256, 0, stream>>>(x, wbf, out);
    } else {
        mll_kernel_f32<<<grid, 256, 0, stream>>>(x, ids, w, out);
    }
}